// Round 1
// baseline (50.712 us; speedup 1.0000x reference)
//
#include <hip/hip_runtime.h>
#include <hip/hip_bf16.h>

#define B_ 2
#define S_ 1024
#define E_ 768
#define H_ 12

typedef __bf16  bf16x8 __attribute__((ext_vector_type(8)));
typedef float   f32x4  __attribute__((ext_vector_type(4)));

__device__ __forceinline__ unsigned short f2bf(float f) {
    union { float f; unsigned u; } a; a.f = f;
    unsigned u = a.u;
    u += 0x7FFFu + ((u >> 16) & 1u);   // RNE
    return (unsigned short)(u >> 16);
}

// ---------------- cast q,k (fp32 -> bf16), z selects which ----------------
__global__ __launch_bounds__(256) void cast_in_kernel(
    const float* __restrict__ q, const float* __restrict__ k,
    unsigned short* __restrict__ qbf, unsigned short* __restrict__ kbf)
{
    const float* src = blockIdx.z ? k : q;
    unsigned short* dst = blockIdx.z ? kbf : qbf;
    int i = (blockIdx.x * 256 + threadIdx.x) * 4;
    float4 v = *(const float4*)(src + i);
    ushort4 o = make_ushort4(f2bf(v.x), f2bf(v.y), f2bf(v.z), f2bf(v.w));
    *(ushort4*)(dst + i) = o;
}

// -------- prep weights: Wq scaled by w_n = lin_w[(n%64)>>3]/sqrt(8); Wk plain; bq scaled --------
__global__ __launch_bounds__(256) void prep_w_kernel(
    const float* __restrict__ Wq, const float* __restrict__ bq,
    const float* __restrict__ Wk, const float* __restrict__ lin_w,
    unsigned short* __restrict__ Wqbf, unsigned short* __restrict__ Wkbf,
    float* __restrict__ bqs)
{
    const float invs = 0.35355339059327373f; // 1/sqrt(8)
    int idx4 = blockIdx.x * 256 + threadIdx.x;
    int i = idx4 * 4;
    if (blockIdx.z == 0) {
        int n = i / E_;                 // output channel (row of W)
        float w = lin_w[(n & 63) >> 3] * invs;
        float4 v = *(const float4*)(Wq + i);
        ushort4 o = make_ushort4(f2bf(v.x * w), f2bf(v.y * w), f2bf(v.z * w), f2bf(v.w * w));
        *(ushort4*)(Wqbf + i) = o;
        if (idx4 < E_) bqs[idx4] = bq[idx4] * (lin_w[(idx4 & 63) >> 3] * invs);
    } else {
        float4 v = *(const float4*)(Wk + i);
        ushort4 o = make_ushort4(f2bf(v.x), f2bf(v.y), f2bf(v.z), f2bf(v.w));
        *(ushort4*)(Wkbf + i) = o;
    }
}

// ---------------- shared GEMM helpers (128x128 tile, BK=64, XOR-swizzled LDS) ----------------
// LDS tile: 128 rows x 64 bf16 cols = 16KB, stored as 8x 16B chunks/row.
// Physical chunk (row, cb) holds global chunk (row, cb ^ (row&7))  -> 2-way-free ds_read_b128.
__device__ __forceinline__ void stage_tile(const unsigned short* __restrict__ g,
                                           int ld, char* lbase, int tid)
{
#pragma unroll
    for (int pass = 0; pass < 4; ++pass) {
        int c = pass * 256 + tid;
        int row = c >> 3, cb = c & 7;
        int cbg = cb ^ (row & 7);
        const unsigned short* src = g + row * ld + cbg * 8;
        __builtin_amdgcn_global_load_lds(
            (const __attribute__((address_space(1))) void*)src,
            (__attribute__((address_space(3))) void*)(lbase + c * 16),
            16, 0, 0);
    }
}

__device__ __forceinline__ bf16x8 ld_frag(const char* lbase, int row, int kk, int lane) {
    int cbyte = (kk * 64 + ((lane >> 4) * 16)) ^ ((row & 7) << 4);
    return *(const bf16x8*)(lbase + row * 128 + cbyte);
}

// ---------------- projection GEMM: P[m,n] = sum_k X[m,k]*W[n,k] + bias[n], bf16 out ----------------
__global__ __launch_bounds__(256) void proj_kernel(
    const unsigned short* __restrict__ qbf, const unsigned short* __restrict__ kbf,
    const unsigned short* __restrict__ Wqbf, const unsigned short* __restrict__ Wkbf,
    const float* __restrict__ bqs, const float* __restrict__ bk,
    unsigned short* __restrict__ qs, unsigned short* __restrict__ kp)
{
    __shared__ char lds[2 * 128 * 64 * 2];
    char* As = lds;
    char* Bs = lds + 128 * 64 * 2;

    const unsigned short* X = blockIdx.z ? kbf : qbf;
    const unsigned short* W = blockIdx.z ? Wkbf : Wqbf;
    const float* bias       = blockIdx.z ? bk : bqs;
    unsigned short* P       = blockIdx.z ? kp : qs;

    int tid = threadIdx.x, lane = tid & 63, wid = tid >> 6;
    int wr = wid >> 1, wc = wid & 1;
    int tm = blockIdx.y * 128, tn = blockIdx.x * 128;

    f32x4 acc[4][4];
#pragma unroll
    for (int n = 0; n < 4; ++n) {
        float bv = bias[tn + wc * 64 + n * 16 + (lane & 15)];
#pragma unroll
        for (int m = 0; m < 4; ++m) acc[m][n] = f32x4{bv, bv, bv, bv};
    }

    for (int kb = 0; kb < E_; kb += 64) {
        stage_tile(X + tm * E_ + kb, E_, As, tid);
        stage_tile(W + tn * E_ + kb, E_, Bs, tid);
        __syncthreads();
#pragma unroll
        for (int kk = 0; kk < 2; ++kk) {
            bf16x8 a[4], b[4];
#pragma unroll
            for (int m = 0; m < 4; ++m) a[m] = ld_frag(As, wr * 64 + m * 16 + (lane & 15), kk, lane);
#pragma unroll
            for (int n = 0; n < 4; ++n) b[n] = ld_frag(Bs, wc * 64 + n * 16 + (lane & 15), kk, lane);
#pragma unroll
            for (int m = 0; m < 4; ++m)
#pragma unroll
                for (int n = 0; n < 4; ++n)
                    acc[m][n] = __builtin_amdgcn_mfma_f32_16x16x32_bf16(a[m], b[n], acc[m][n], 0, 0, 0);
        }
        __syncthreads();
    }

#pragma unroll
    for (int m = 0; m < 4; ++m)
#pragma unroll
        for (int n = 0; n < 4; ++n) {
            int col = tn + wc * 64 + n * 16 + (lane & 15);
            int rbase = tm + wr * 64 + m * 16 + ((lane >> 4) << 2);
#pragma unroll
            for (int r = 0; r < 4; ++r)
                P[(rbase + r) * E_ + col] = f2bf(acc[m][n][r]);
        }
}

// ---------------- scores: per (b,h): out = qs_h @ kp_h^T + lin_b, fp32 out ----------------
__global__ __launch_bounds__(256) void scores_kernel(
    const unsigned short* __restrict__ qs, const unsigned short* __restrict__ kp,
    const float* __restrict__ lin_b, float* __restrict__ out)
{
    __shared__ char lds[2 * 128 * 64 * 2];
    char* As = lds;
    char* Bs = lds + 128 * 64 * 2;

    int z = blockIdx.z;                 // b*12 + h
    int b = z / H_, h = z - b * H_;
    int tid = threadIdx.x, lane = tid & 63, wid = tid >> 6;
    int wr = wid >> 1, wc = wid & 1;
    int ti = blockIdx.y * 128, tj = blockIdx.x * 128;

    const unsigned short* Q = qs + (size_t)(b * S_ + ti) * E_ + h * 64;
    const unsigned short* K = kp + (size_t)(b * S_ + tj) * E_ + h * 64;
    stage_tile(Q, E_, As, tid);
    stage_tile(K, E_, Bs, tid);

    float lb = lin_b[0];
    f32x4 acc[4][4];
#pragma unroll
    for (int m = 0; m < 4; ++m)
#pragma unroll
        for (int n = 0; n < 4; ++n) acc[m][n] = f32x4{lb, lb, lb, lb};

    __syncthreads();
#pragma unroll
    for (int kk = 0; kk < 2; ++kk) {
        bf16x8 a[4], bfr[4];
#pragma unroll
        for (int m = 0; m < 4; ++m) a[m] = ld_frag(As, wr * 64 + m * 16 + (lane & 15), kk, lane);
#pragma unroll
        for (int n = 0; n < 4; ++n) bfr[n] = ld_frag(Bs, wc * 64 + n * 16 + (lane & 15), kk, lane);
#pragma unroll
        for (int m = 0; m < 4; ++m)
#pragma unroll
            for (int n = 0; n < 4; ++n)
                acc[m][n] = __builtin_amdgcn_mfma_f32_16x16x32_bf16(a[m], bfr[n], acc[m][n], 0, 0, 0);
    }

    float* O = out + ((size_t)z << 20);
#pragma unroll
    for (int m = 0; m < 4; ++m)
#pragma unroll
        for (int n = 0; n < 4; ++n) {
            int col = tj + wc * 64 + n * 16 + (lane & 15);
            int rbase = ti + wr * 64 + m * 16 + ((lane >> 4) << 2);
#pragma unroll
            for (int r = 0; r < 4; ++r)
                O[(size_t)(rbase + r) * S_ + col] = acc[m][n][r];
        }
}

extern "C" void kernel_launch(void* const* d_in, const int* in_sizes, int n_in,
                              void* d_out, int out_size, void* d_ws, size_t ws_size,
                              hipStream_t stream)
{
    const float* k_in  = (const float*)d_in[0];
    const float* q_in  = (const float*)d_in[1];
    const float* Wq_w  = (const float*)d_in[2];
    const float* Wq_b  = (const float*)d_in[3];
    const float* Wk_w  = (const float*)d_in[4];
    const float* Wk_b  = (const float*)d_in[5];
    const float* lin_w = (const float*)d_in[6];
    const float* lin_b = (const float*)d_in[7];
    float* out = (float*)d_out;

    char* ws = (char*)d_ws;
    unsigned short* qbf  = (unsigned short*)(ws + 0);
    unsigned short* kbf  = (unsigned short*)(ws + 3145728);
    unsigned short* Wqbf = (unsigned short*)(ws + 6291456);
    unsigned short* Wkbf = (unsigned short*)(ws + 7471104);
    float*          bqs  = (float*)        (ws + 8650752);
    unsigned short* qsb  = (unsigned short*)(ws + 8653824);
    unsigned short* kpb  = (unsigned short*)(ws + 11799552);

    // 1) cast q,k to bf16
    cast_in_kernel<<<dim3(1536, 1, 2), dim3(256), 0, stream>>>(q_in, k_in, qbf, kbf);
    // 2) prep weights (fold lin_w*scale into Wq + bq)
    prep_w_kernel<<<dim3(576, 1, 2), dim3(256), 0, stream>>>(Wq_w, Wq_b, Wk_w, lin_w, Wqbf, Wkbf, bqs);
    // 3) projections: qs = (q@Wq^T + bq) * w  ;  kp = k@Wk^T + bk   (bf16 out)
    proj_kernel<<<dim3(6, 16, 2), dim3(256), 0, stream>>>(qbf, kbf, Wqbf, Wkbf, bqs, Wk_b, qsb, kpb);
    // 4) scores: out[b,h] = qs_h @ kp_h^T + lin_b   (fp32 out, 96MB)
    scores_kernel<<<dim3(8, 8, 24), dim3(256), 0, stream>>>(qsb, kpb, lin_b, out);
}

// Round 2
// 49.723 us; speedup vs baseline: 1.0199x; 1.0199x over previous
//
#include <hip/hip_runtime.h>
#include <hip/hip_bf16.h>

#define B_ 2
#define S_ 1024
#define E_ 768
#define H_ 12

typedef __bf16  bf16x8 __attribute__((ext_vector_type(8)));
typedef float   f32x4  __attribute__((ext_vector_type(4)));
typedef unsigned short u16x8 __attribute__((ext_vector_type(8)));

__device__ __forceinline__ unsigned short f2bf(float f) {
    union { float f; unsigned u; } a; a.f = f;
    unsigned u = a.u;
    u += 0x7FFFu + ((u >> 16) & 1u);   // RNE
    return (unsigned short)(u >> 16);
}

// -------- prep weights: Wq scaled by w_n = lin_w[(n%64)>>3]/sqrt(8); Wk plain; bq scaled --------
__global__ __launch_bounds__(256) void prep_w_kernel(
    const float* __restrict__ Wq, const float* __restrict__ bq,
    const float* __restrict__ Wk, const float* __restrict__ lin_w,
    unsigned short* __restrict__ Wqbf, unsigned short* __restrict__ Wkbf,
    float* __restrict__ bqs)
{
    const float invs = 0.35355339059327373f; // 1/sqrt(8)
    int idx4 = blockIdx.x * 256 + threadIdx.x;
    int i = idx4 * 4;
    if (blockIdx.z == 0) {
        int n = i / E_;                 // output channel (row of W)
        float w = lin_w[(n & 63) >> 3] * invs;
        float4 v = *(const float4*)(Wq + i);
        ushort4 o = make_ushort4(f2bf(v.x * w), f2bf(v.y * w), f2bf(v.z * w), f2bf(v.w * w));
        *(ushort4*)(Wqbf + i) = o;
        if (idx4 < E_) bqs[idx4] = bq[idx4] * (lin_w[(idx4 & 63) >> 3] * invs);
    } else {
        float4 v = *(const float4*)(Wk + i);
        ushort4 o = make_ushort4(f2bf(v.x), f2bf(v.y), f2bf(v.z), f2bf(v.w));
        *(ushort4*)(Wkbf + i) = o;
    }
}

// ---------------- LDS helpers ----------------
// Tile: R rows x 64 bf16 cols, row = 128B = 8x16B chunks.
// Physical chunk (row, cb) holds global chunk (row, cb ^ (row&7)) -> conflict-light ds_read_b128.

// stage a 64x64 bf16 tile from fp32 global (reg-staged: load fp32, cvt, ds_write swizzled)
__device__ __forceinline__ void stage_x64_f32(const float* __restrict__ g,
                                              int ld, char* lbase, int tid)
{
#pragma unroll
    for (int pass = 0; pass < 2; ++pass) {
        int c = pass * 256 + tid;
        int row = c >> 3, cb = c & 7;
        int cbg = cb ^ (row & 7);
        const float* src = g + row * ld + cbg * 8;
        float4 v0 = *(const float4*)(src);
        float4 v1 = *(const float4*)(src + 4);
        u16x8 o;
        o[0] = f2bf(v0.x); o[1] = f2bf(v0.y); o[2] = f2bf(v0.z); o[3] = f2bf(v0.w);
        o[4] = f2bf(v1.x); o[5] = f2bf(v1.y); o[6] = f2bf(v1.z); o[7] = f2bf(v1.w);
        *(u16x8*)(lbase + c * 16) = o;
    }
}

// stage a 64x64 bf16 tile from bf16 global via global_load_lds (2 passes)
__device__ __forceinline__ void stage_w64(const unsigned short* __restrict__ g,
                                          int ld, char* lbase, int tid)
{
#pragma unroll
    for (int pass = 0; pass < 2; ++pass) {
        int c = pass * 256 + tid;
        int row = c >> 3, cb = c & 7;
        int cbg = cb ^ (row & 7);
        const unsigned short* src = g + row * ld + cbg * 8;
        __builtin_amdgcn_global_load_lds(
            (const __attribute__((address_space(1))) void*)src,
            (__attribute__((address_space(3))) void*)(lbase + c * 16),
            16, 0, 0);
    }
}

// stage a 128x64 bf16 tile from bf16 global via global_load_lds (4 passes)
__device__ __forceinline__ void stage_w128(const unsigned short* __restrict__ g,
                                           int ld, char* lbase, int tid)
{
#pragma unroll
    for (int pass = 0; pass < 4; ++pass) {
        int c = pass * 256 + tid;
        int row = c >> 3, cb = c & 7;
        int cbg = cb ^ (row & 7);
        const unsigned short* src = g + row * ld + cbg * 8;
        __builtin_amdgcn_global_load_lds(
            (const __attribute__((address_space(1))) void*)src,
            (__attribute__((address_space(3))) void*)(lbase + c * 16),
            16, 0, 0);
    }
}

__device__ __forceinline__ bf16x8 ld_frag(const char* lbase, int row, int kk, int lane) {
    int cbyte = (kk * 64 + ((lane >> 4) * 16)) ^ ((row & 7) << 4);
    return *(const bf16x8*)(lbase + row * 128 + cbyte);
}

// ---------------- projection GEMM: P[m,n] = sum_k X[m,k]*W[n,k] + bias[n], bf16 out ----------------
// 64x64 tile, 4 waves (2x2), each wave 32x32. X reg-staged from fp32; W via global_load_lds.
__global__ __launch_bounds__(256) void proj_kernel(
    const float* __restrict__ q_in, const float* __restrict__ k_in,
    const unsigned short* __restrict__ Wqbf, const unsigned short* __restrict__ Wkbf,
    const float* __restrict__ bqs, const float* __restrict__ bk,
    unsigned short* __restrict__ qs, unsigned short* __restrict__ kp)
{
    __shared__ char lds[2 * 64 * 64 * 2];   // As + Bs, 8KB each
    char* As = lds;
    char* Bs = lds + 64 * 64 * 2;

    const float* X          = blockIdx.z ? k_in : q_in;
    const unsigned short* W = blockIdx.z ? Wkbf : Wqbf;
    const float* bias       = blockIdx.z ? bk : bqs;
    unsigned short* P       = blockIdx.z ? kp : qs;

    int tid = threadIdx.x, lane = tid & 63, wid = tid >> 6;
    int wr = wid >> 1, wc = wid & 1;
    int tm = blockIdx.y * 64, tn = blockIdx.x * 64;

    f32x4 acc[2][2];
#pragma unroll
    for (int n = 0; n < 2; ++n) {
        float bv = bias[tn + wc * 32 + n * 16 + (lane & 15)];
#pragma unroll
        for (int m = 0; m < 2; ++m) acc[m][n] = f32x4{bv, bv, bv, bv};
    }

    for (int kb = 0; kb < E_; kb += 64) {
        stage_x64_f32(X + (size_t)tm * E_ + kb, E_, As, tid);
        stage_w64(W + (size_t)tn * E_ + kb, E_, Bs, tid);
        __syncthreads();
#pragma unroll
        for (int kk = 0; kk < 2; ++kk) {
            bf16x8 a[2], b[2];
#pragma unroll
            for (int m = 0; m < 2; ++m) a[m] = ld_frag(As, wr * 32 + m * 16 + (lane & 15), kk, lane);
#pragma unroll
            for (int n = 0; n < 2; ++n) b[n] = ld_frag(Bs, wc * 32 + n * 16 + (lane & 15), kk, lane);
#pragma unroll
            for (int m = 0; m < 2; ++m)
#pragma unroll
                for (int n = 0; n < 2; ++n)
                    acc[m][n] = __builtin_amdgcn_mfma_f32_16x16x32_bf16(a[m], b[n], acc[m][n], 0, 0, 0);
        }
        __syncthreads();
    }

#pragma unroll
    for (int m = 0; m < 2; ++m)
#pragma unroll
        for (int n = 0; n < 2; ++n) {
            int col = tn + wc * 32 + n * 16 + (lane & 15);
            int rbase = tm + wr * 32 + m * 16 + ((lane >> 4) << 2);
#pragma unroll
            for (int r = 0; r < 4; ++r)
                P[(size_t)(rbase + r) * E_ + col] = f2bf(acc[m][n][r]);
        }
}

// ---------------- scores: per (b,h): out = qs_h @ kp_h^T + lin_b, fp32 out ----------------
__global__ __launch_bounds__(256) void scores_kernel(
    const unsigned short* __restrict__ qs, const unsigned short* __restrict__ kp,
    const float* __restrict__ lin_b, float* __restrict__ out)
{
    __shared__ char lds[2 * 128 * 64 * 2];  // 16KB + 16KB
    char* As = lds;
    char* Bs = lds + 128 * 64 * 2;

    int z = blockIdx.z;                 // b*12 + h
    int b = z / H_, h = z - b * H_;
    int tid = threadIdx.x, lane = tid & 63, wid = tid >> 6;
    int wr = wid >> 1, wc = wid & 1;
    int ti = blockIdx.y * 128, tj = blockIdx.x * 128;

    const unsigned short* Q = qs + (size_t)(b * S_ + ti) * E_ + h * 64;
    const unsigned short* K = kp + (size_t)(b * S_ + tj) * E_ + h * 64;
    stage_w128(Q, E_, As, tid);
    stage_w128(K, E_, Bs, tid);

    float lb = lin_b[0];
    f32x4 acc[4][4];
#pragma unroll
    for (int m = 0; m < 4; ++m)
#pragma unroll
        for (int n = 0; n < 4; ++n) acc[m][n] = f32x4{lb, lb, lb, lb};

    __syncthreads();
#pragma unroll
    for (int kk = 0; kk < 2; ++kk) {
        bf16x8 a[4], bfr[4];
#pragma unroll
        for (int m = 0; m < 4; ++m) a[m] = ld_frag(As, wr * 64 + m * 16 + (lane & 15), kk, lane);
#pragma unroll
        for (int n = 0; n < 4; ++n) bfr[n] = ld_frag(Bs, wc * 64 + n * 16 + (lane & 15), kk, lane);
#pragma unroll
        for (int m = 0; m < 4; ++m)
#pragma unroll
            for (int n = 0; n < 4; ++n)
                acc[m][n] = __builtin_amdgcn_mfma_f32_16x16x32_bf16(a[m], bfr[n], acc[m][n], 0, 0, 0);
    }

    float* O = out + ((size_t)z << 20);
#pragma unroll
    for (int m = 0; m < 4; ++m)
#pragma unroll
        for (int n = 0; n < 4; ++n) {
            int col = tj + wc * 64 + n * 16 + (lane & 15);
            int rbase = ti + wr * 64 + m * 16 + ((lane >> 4) << 2);
#pragma unroll
            for (int r = 0; r < 4; ++r)
                O[(size_t)(rbase + r) * S_ + col] = acc[m][n][r];
        }
}

extern "C" void kernel_launch(void* const* d_in, const int* in_sizes, int n_in,
                              void* d_out, int out_size, void* d_ws, size_t ws_size,
                              hipStream_t stream)
{
    const float* k_in  = (const float*)d_in[0];
    const float* q_in  = (const float*)d_in[1];
    const float* Wq_w  = (const float*)d_in[2];
    const float* Wq_b  = (const float*)d_in[3];
    const float* Wk_w  = (const float*)d_in[4];
    const float* Wk_b  = (const float*)d_in[5];
    const float* lin_w = (const float*)d_in[6];
    const float* lin_b = (const float*)d_in[7];
    float* out = (float*)d_out;

    char* ws = (char*)d_ws;
    unsigned short* Wqbf = (unsigned short*)(ws + 0);
    unsigned short* Wkbf = (unsigned short*)(ws + 1179648);
    float*          bqs  = (float*)        (ws + 2359296);
    unsigned short* qsb  = (unsigned short*)(ws + 2362368);
    unsigned short* kpb  = (unsigned short*)(ws + 5508096);

    // 1) prep weights (fold lin_w*scale into Wq + bq; cast both W to bf16)
    prep_w_kernel<<<dim3(576, 1, 2), dim3(256), 0, stream>>>(Wq_w, Wq_b, Wk_w, lin_w, Wqbf, Wkbf, bqs);
    // 2) projections (fp32 X read directly, cvt in-kernel): qs = (q@Wq^T+bq)*w ; kp = k@Wk^T+bk
    proj_kernel<<<dim3(12, 32, 2), dim3(256), 0, stream>>>(q_in, k_in, Wqbf, Wkbf, bqs, Wk_b, qsb, kpb);
    // 3) scores: out[b,h] = qs_h @ kp_h^T + lin_b   (fp32 out, 96MB)
    scores_kernel<<<dim3(8, 8, 24), dim3(256), 0, stream>>>(qsb, kpb, lin_b, out);
}